// Round 1
// 677.383 us; speedup vs baseline: 1.0302x; 1.0302x over previous
//
#include <hip/hip_runtime.h>
#include <math.h>

#define NK    21
#define TILE  64
#define HALO  4
#define IN_W  72          // TILE + 2*HALO
#define SCR_W 76          // padded sScr stride: bank-stride 12, 16B-aligned
#define HW    512

typedef float f32x4 __attribute__((ext_vector_type(4)));

struct GParams {
    float g[NK][5];   // g[i][d] = weight at distance d (0..R), 0 beyond
    int   R[NK];      // effective radius, 1..4
};

__device__ __forceinline__ int refl(int v) {
    v = (v < 0) ? -v : v;
    return (v > HW - 1) ? (2 * (HW - 1) - v) : v;
}

// Vertical pass, vectorized: sIn (72x72) -> sScr (64 x SCR_W).
// Tasks: 16 row-groups (4 rows) x 18 col-groups (4 cols) = 288, f32x4 b128 I/O.
template<int R>
__device__ __forceinline__ void vpass(const float* sIn, float* sScr,
                                      const float g[5], int tid) {
    constexpr int WIN = 4 + 2 * R;
    for (int t = tid; t < 16 * 18; t += 256) {
        int rg = t / 18;
        int cg = t - rg * 18;
        const f32x4* src = (const f32x4*)(sIn + (4 * rg + HALO - R) * IN_W) + cg;
        f32x4 win[WIN];
        #pragma unroll
        for (int j = 0; j < WIN; ++j) win[j] = src[j * (IN_W / 4)];
        f32x4* dst = (f32x4*)(sScr + (4 * rg) * SCR_W) + cg;
        #pragma unroll
        for (int s = 0; s < 4; ++s) {
            f32x4 acc = g[0] * win[s + R];
            #pragma unroll
            for (int d = 1; d <= R; ++d)
                acc += g[d] * (win[s + R - d] + win[s + R + d]);
            dst[s * (SCR_W / 4)] = acc;
        }
    }
}

// Horizontal pass: sScr (64 x SCR_W, col c == global x0-4+c) -> global out plane.
// Tasks: 64 rows x 8 col-groups of 8. Window = 16 contiguous floats (4x b128).
template<int R>
__device__ __forceinline__ void hpass(const float* sScr, float* op,
                                      const float g[5], int tid, int y0, int x0) {
    for (int t = tid; t < 512; t += 256) {
        int r  = t >> 3;
        int w0 = (t & 7) << 3;
        const f32x4* rp = (const f32x4*)(sScr + r * SCR_W + w0);
        f32x4 A = rp[0], B = rp[1], C = rp[2], D = rp[3];
        float win[16] = {A.x, A.y, A.z, A.w, B.x, B.y, B.z, B.w,
                         C.x, C.y, C.z, C.w, D.x, D.y, D.z, D.w};
        float o[8];
        #pragma unroll
        for (int u = 0; u < 8; ++u) {
            float acc = g[0] * win[u + 4];
            #pragma unroll
            for (int d = 1; d <= R; ++d)
                acc += g[d] * (win[u + 4 - d] + win[u + 4 + d]);
            o[u] = acc;
        }
        float* po = op + (y0 + r) * HW + x0 + w0;
        f32x4 v0 = {o[0], o[1], o[2], o[3]};
        f32x4 v1 = {o[4], o[5], o[6], o[7]};
        __builtin_nontemporal_store(v0, (f32x4*)po);
        __builtin_nontemporal_store(v1, (f32x4*)po + 1);
    }
}

// One block per (plane, tile, j). j in [0,20] = gaussian j; j == 21 = identity copy.
// bid = (plane*64 + tile)*22 + j  -> the 22 blocks of one tile are adjacent in
// dispatch order, so their shared 72x72 input tile is L2-hot across XCDs.
__global__ __launch_bounds__(256, 4)
void gauss_all(const float* __restrict__ x, float* __restrict__ out, GParams P) {
    __shared__ float sIn[IN_W * IN_W];    // 20.25 KB
    __shared__ float sScr[TILE * SCR_W];  // 19.00 KB  (total 39.25 KB -> 4 blk/CU)
    const int tid = threadIdx.x;
    const int bid = blockIdx.x;
    const int tg  = bid / 22;             // plane*64 + tile
    const int j   = bid - tg * 22;        // 0..21
    const int plane = tg >> 6;            // 0..23  (b*3 + c)
    const int tile  = tg & 63;
    const int bb = plane / 3, cc = plane - 3 * bb;
    const int y0 = (tile >> 3) << 6;
    const int x0 = (tile & 7) << 6;
    const float* ip = x + (size_t)plane * (HW * HW);

    if (j == NK) {
        // identity channel: direct tile copy, no LDS, no barriers
        float* op = out + (size_t)(bb * 66 + cc) * (HW * HW);
        for (int t = tid; t < 1024; t += 256) {
            int r = t >> 4, c4 = (t & 15) << 2;
            f32x4 v = *(const f32x4*)(ip + (y0 + r) * HW + x0 + c4);
            __builtin_nontemporal_store(v, (f32x4*)(op + (y0 + r) * HW + x0 + c4));
        }
        return;
    }

    // stage reflect-padded 72x72 input tile
    for (int t = tid; t < IN_W * IN_W; t += 256) {
        int ir = t / IN_W;
        int ic = t - ir * IN_W;
        sIn[t] = ip[refl(y0 - HALO + ir) * HW + refl(x0 - HALO + ic)];
    }
    __syncthreads();

    float g[5];
    #pragma unroll
    for (int d = 0; d < 5; ++d) g[d] = P.g[j][d];
    float* op = out + (size_t)(bb * 66 + 3 + 3 * j + cc) * (HW * HW);

    switch (P.R[j]) {
        case 1: vpass<1>(sIn, sScr, g, tid); __syncthreads();
                hpass<1>(sScr, op, g, tid, y0, x0); break;
        case 2: vpass<2>(sIn, sScr, g, tid); __syncthreads();
                hpass<2>(sScr, op, g, tid, y0, x0); break;
        case 3: vpass<3>(sIn, sScr, g, tid); __syncthreads();
                hpass<3>(sScr, op, g, tid, y0, x0); break;
        default: vpass<4>(sIn, sScr, g, tid); __syncthreads();
                hpass<4>(sScr, op, g, tid, y0, x0); break;
    }
}

static GParams make_params() {
    GParams P;
    const double inc = 18.0 / 19.0;   // (MAX-INIT)/(NUM-2), replicate Python doubles
    for (int i = 0; i < NK; ++i) {
        double f1 = (double)i * inc;
        double f3 = floor(f1 / 2.0) * 2.0;
        int ks = (int)(3.0 + f3);
        if (ks > 21) ks = 21;
        int p = (ks - 1) / 2;
        double sig = 0.5 + 0.025 * (double)i;
        double s2  = 2.0 * sig * sig;
        double S = 0.0;
        for (int m = -p; m <= p; ++m) S += exp(-(double)(m * m) / s2);
        // minimal R with dropped tail mass <= 3e-4 (per axis), capped at 4
        int R = p;
        for (int r = 1; r <= p; ++r) {
            double Sr = 0.0;
            for (int m = -r; m <= r; ++m) Sr += exp(-(double)(m * m) / s2);
            if ((S - Sr) / S <= 3e-4) { R = r; break; }
        }
        if (R > 4) R = 4;
        P.R[i] = R;
        for (int d = 0; d < 5; ++d)
            P.g[i][d] = (d <= R) ? (float)(exp(-(double)(d * d) / s2) / S) : 0.0f;
    }
    return P;
}

extern "C" void kernel_launch(void* const* d_in, const int* in_sizes, int n_in,
                              void* d_out, int out_size, void* d_ws, size_t ws_size,
                              hipStream_t stream) {
    const float* x = (const float*)d_in[0];
    float* out = (float*)d_out;
    GParams P = make_params();   // cheap host math, identical every call
    gauss_all<<<dim3(24 * 64 * 22), dim3(256), 0, stream>>>(x, out, P);
}

// Round 2
// 655.913 us; speedup vs baseline: 1.0639x; 1.0327x over previous
//
#include <hip/hip_runtime.h>
#include <math.h>

#define NK 21
#define HW 512

typedef float f32x4 __attribute__((ext_vector_type(4)));

struct GParams {
    float g[NK][5];   // g[i][d] = weight at distance d (0..R), 0 beyond (exact zeros)
    int   R[NK];      // effective radius (unused on device: R=4 uniform w/ zero tails)
};

__device__ __forceinline__ int refl(int v) {
    v = (v < 0) ? -v : v;
    return (v > HW - 1) ? (2 * (HW - 1) - v) : v;
}

// Zero-LDS, zero-barrier design: each wave owns one full 512-px output row.
// Lane l computes output cols [8l, 8l+7]; it holds the reflect-padded
// 9-row x 16-col input window entirely in registers (36 x f32x4 = 144 VGPR).
// All 21 gaussians + identity are computed from that one register window.
// Vertical pass uses zero-padded weights at uniform R=4: adding g[d]=0 terms
// in the same ascending-d order is bit-identical to the R-truncated sum.
__global__ __launch_bounds__(256, 2)
void gauss_all(const float* __restrict__ x, float* __restrict__ out, GParams P) {
    const int tid   = threadIdx.x;
    const int lane  = tid & 63;
    const int wid   = tid >> 6;
    const int bid   = blockIdx.x;
    const int plane = bid >> 7;           // 24 planes (b*3+c), 128 row-blocks each
    const int rb    = bid & 127;
    const int y     = rb * 4 + wid;       // this wave's output row (wave-uniform)
    const int bb    = plane / 3, cc = plane - 3 * bb;
    const int x0    = lane << 3;          // first output col of this lane
    const float* ip = x + (size_t)plane * (HW * HW);

    // ---- load 9 input rows x 16 cols (x0-4 .. x0+11), reflect-padded ----
    f32x4 win[9][4];
    #pragma unroll
    for (int dy = 0; dy < 9; ++dy) {
        const float* rp = ip + (size_t)refl(y - 4 + dy) * HW;
        if (lane >= 1 && lane <= 62) {
            // interior: (x0-4)*4 bytes = 32*lane - 16 -> 16B aligned
            const f32x4* vp = (const f32x4*)(rp + x0 - 4);
            win[dy][0] = vp[0]; win[dy][1] = vp[1];
            win[dy][2] = vp[2]; win[dy][3] = vp[3];
        } else {
            // border lanes 0 and 63: per-element column reflect (once per thread)
            #pragma unroll
            for (int q = 0; q < 4; ++q) {
                f32x4 v;
                #pragma unroll
                for (int e = 0; e < 4; ++e)
                    v[e] = rp[refl(x0 - 4 + q * 4 + e)];
                win[dy][q] = v;
            }
        }
    }

    // ---- identity channel: window cols 4..11 == global cols x0..x0+7 ----
    {
        float* po = out + (size_t)(bb * 66 + cc) * (HW * HW) + (size_t)y * HW + x0;
        __builtin_nontemporal_store(win[4][1], (f32x4*)po);
        __builtin_nontemporal_store(win[4][2], (f32x4*)po + 1);
    }

    // ---- all 21 gaussians from the register window ----
    #pragma unroll 1
    for (int j = 0; j < NK; ++j) {
        const float g0 = P.g[j][0], g1 = P.g[j][1], g2 = P.g[j][2],
                    g3 = P.g[j][3], g4 = P.g[j][4];
        // vertical: 16 cols as 4 quads
        f32x4 h[4];
        #pragma unroll
        for (int q = 0; q < 4; ++q) {
            f32x4 acc = g0 * win[4][q];
            acc += g1 * (win[3][q] + win[5][q]);
            acc += g2 * (win[2][q] + win[6][q]);
            acc += g3 * (win[1][q] + win[7][q]);
            acc += g4 * (win[0][q] + win[8][q]);
            h[q] = acc;
        }
        float hr[16] = {h[0].x, h[0].y, h[0].z, h[0].w,
                        h[1].x, h[1].y, h[1].z, h[1].w,
                        h[2].x, h[2].y, h[2].z, h[2].w,
                        h[3].x, h[3].y, h[3].z, h[3].w};
        // horizontal: in-register sliding window, fully unrolled (static idx)
        float o[8];
        #pragma unroll
        for (int u = 0; u < 8; ++u) {
            float acc = g0 * hr[u + 4];
            acc += g1 * (hr[u + 3] + hr[u + 5]);
            acc += g2 * (hr[u + 2] + hr[u + 6]);
            acc += g3 * (hr[u + 1] + hr[u + 7]);
            acc += g4 * (hr[u + 0] + hr[u + 8]);
            o[u] = acc;
        }
        float* po = out + (size_t)(bb * 66 + 3 + 3 * j + cc) * (HW * HW)
                        + (size_t)y * HW + x0;
        f32x4 v0 = {o[0], o[1], o[2], o[3]};
        f32x4 v1 = {o[4], o[5], o[6], o[7]};
        __builtin_nontemporal_store(v0, (f32x4*)po);
        __builtin_nontemporal_store(v1, (f32x4*)po + 1);
    }
}

static GParams make_params() {
    GParams P;
    const double inc = 18.0 / 19.0;   // (MAX-INIT)/(NUM-2), replicate Python doubles
    for (int i = 0; i < NK; ++i) {
        double f1 = (double)i * inc;
        double f3 = floor(f1 / 2.0) * 2.0;
        int ks = (int)(3.0 + f3);
        if (ks > 21) ks = 21;
        int p = (ks - 1) / 2;
        double sig = 0.5 + 0.025 * (double)i;
        double s2  = 2.0 * sig * sig;
        double S = 0.0;
        for (int m = -p; m <= p; ++m) S += exp(-(double)(m * m) / s2);
        // minimal R with dropped tail mass <= 3e-4 (per axis), capped at 4
        int R = p;
        for (int r = 1; r <= p; ++r) {
            double Sr = 0.0;
            for (int m = -r; m <= r; ++m) Sr += exp(-(double)(m * m) / s2);
            if ((S - Sr) / S <= 3e-4) { R = r; break; }
        }
        if (R > 4) R = 4;
        P.R[i] = R;
        for (int d = 0; d < 5; ++d)
            P.g[i][d] = (d <= R) ? (float)(exp(-(double)(d * d) / s2) / S) : 0.0f;
    }
    return P;
}

extern "C" void kernel_launch(void* const* d_in, const int* in_sizes, int n_in,
                              void* d_out, int out_size, void* d_ws, size_t ws_size,
                              hipStream_t stream) {
    const float* x = (const float*)d_in[0];
    float* out = (float*)d_out;
    GParams P = make_params();   // cheap host math, identical every call
    gauss_all<<<dim3(24 * 128), dim3(256), 0, stream>>>(x, out, P);
}